// Round 8
// baseline (247.532 us; speedup 1.0000x reference)
//
#include <hip/hip_runtime.h>
#include <stdint.h>
#include <stddef.h>

typedef float    f32x4 __attribute__((ext_vector_type(4)));
typedef float    f32x2 __attribute__((ext_vector_type(2)));
typedef _Float16 f16x4 __attribute__((ext_vector_type(4)));
typedef _Float16 f16x8 __attribute__((ext_vector_type(8)));
typedef _Float16 f16x2 __attribute__((ext_vector_type(2)));

#define HH 96
#define MROWS 16
#define OSTR 100   // outLDS row stride (dwords)

// Layer-1 neuron permutation: tile T, C-slot m -> actual neuron index, chosen so
// the 16x16x16 layer-1 MFMA C-output lands exactly in the 16x16x32 layer-2
// B-fragment layout (k = kc*32 + lq*8 + j) with zero cross-lane movement:
//   a(2kc+p, 4lq+r) = 32kc + 8lq + 4p + r.
__device__ __forceinline__ int permA(int T, int m) {
    return 32*(T>>1) + 8*(m>>2) + 4*(T&1) + (m&3);
}

__launch_bounds__(256, 2)
__global__ void policy_scan_kernel(
    const float* __restrict__ policy,     // (B,96,4)
    const float* __restrict__ noiseT,     // (B,96)
    const float* __restrict__ noiseD,     // (B,96)
    const float* __restrict__ action_pre, // (B,)
    const float* __restrict__ state_pre,  // (B,)
    const float* __restrict__ Lambda1,    // (1,)
    const float* __restrict__ Budget1,    // (1,)
    const float* __restrict__ W1,         // (256,6)
    const float* __restrict__ b1,         // (256,)
    const float* __restrict__ W2,         // (256,256)
    const float* __restrict__ b2,         // (256,)
    const float* __restrict__ W3,         // (256,)
    const float* __restrict__ b3,         // (1,)
    float* __restrict__ out)              // (B,96)
{
    __shared__ __attribute__((aligned(16))) float partialLDS[64];     // [l16*4+wave]
    __shared__ __attribute__((aligned(16))) float outLDS[MROWS*OSTR]; // 6400 B

    const int tid  = threadIdx.x;          // 0..255
    const int wave = tid >> 6;             // 0..3
    const int lane = tid & 63;
    const int l16  = lane & 15;
    const int lq   = lane >> 4;            // 0..3
    const int r0   = blockIdx.x * MROWS;
    const int row  = r0 + l16;             // this lane's batch row (replicated x16)

    // ---- zero-init ALL LDS we ever read (identical behavior on every launch) ----
    if (tid < 64) partialLDS[tid] = 0.0f;
    #pragma unroll
    for (int i = 0; i < 7; ++i) {
        int j = i*256 + tid;
        if (j < MROWS*OSTR) outLDS[j] = 0.0f;
    }

    // ---- W2 -> fp16 A-frags (A[m=n2][k]): lane (l16,lq) holds
    // W2[n2 = wave*64+tt*16+l16][k = kc*32+lq*8+j]  (128 VGPRs) ----
    f16x8 bfr[4][8];
    #pragma unroll
    for (int tt = 0; tt < 4; ++tt) {
        const int n = wave*64 + tt*16 + l16;
        const float* wrow = W2 + (size_t)n * 256;
        #pragma unroll
        for (int kc = 0; kc < 8; ++kc) {
            const int k0 = kc*32 + lq*8;
            f32x4 u0 = *(const f32x4*)(wrow + k0);
            f32x4 u1 = *(const f32x4*)(wrow + k0 + 4);
            f16x8 v;
            v[0]=(_Float16)u0[0]; v[1]=(_Float16)u0[1]; v[2]=(_Float16)u0[2]; v[3]=(_Float16)u0[3];
            v[4]=(_Float16)u1[0]; v[5]=(_Float16)u1[1]; v[6]=(_Float16)u1[2]; v[7]=(_Float16)u1[3];
            bfr[tt][kc] = v;
        }
    }
    // b2 / W3 per (tt, r): n2 = wave*64 + tt*16 + lq*4 + r
    f32x4 b2v4[4], w3v4[4];
    #pragma unroll
    for (int tt = 0; tt < 4; ++tt) {
        const int nb = wave*64 + tt*16 + lq*4;
        b2v4[tt] = *(const f32x4*)&b2[nb];
        w3v4[tt] = *(const f32x4*)&W3[nb];
    }

    // ---- W1 -> permuted 16x16x16 A-frags (32 VGPRs); bias folded at k=6 ----
    f16x4 w1A[16];
    #pragma unroll
    for (int T = 0; T < 16; ++T) {
        const int a = permA(T, l16);
        f16x4 w = {};
        if (lq == 0) {
            w[0]=(_Float16)W1[a*6+0]; w[1]=(_Float16)W1[a*6+1];
            w[2]=(_Float16)W1[a*6+2]; w[3]=(_Float16)W1[a*6+3];
        } else if (lq == 1) {
            w[0]=(_Float16)W1[a*6+4]; w[1]=(_Float16)W1[a*6+5];
            w[2]=(_Float16)b1[a];     w[3]=(_Float16)0.0f;
        }
        w1A[T] = w;
    }

    const float lam  = Lambda1[0];
    const float budH = Budget1[0] * (1.0f/96.0f);
    const float b3s  = b3[0];
    const float per_step = lam * 2.0f + budH;

    // ---- recurrence state for row l16 (replicated across lq & waves) ----
    float stA = action_pre[row];
    float stS = state_pre[row];
    float stB = per_step, stC = 0.0f, stSS = 0.0f, stAD = 0.0f;

    // first step's features (prefetched; later steps prefetch in-loop)
    f32x4 f = *(const f32x4*)&policy[(size_t)row*(HH*4)];

    __syncthreads();   // LDS init complete before first partial write

    #pragma unroll 1
    for (int t = 0; t < HH; ++t) {
        const float dem = f[0];
        // x B-frag for layer 1 (k = lq*4+j): lq0={feat}, lq1={stA,stS,1,0}
        f16x4 xB = {};
        if (lq == 0) {
            xB[0]=(_Float16)f[0]; xB[1]=(_Float16)f[1];
            xB[2]=(_Float16)f[2]; xB[3]=(_Float16)f[3];
        } else if (lq == 1) {
            xB[0]=(_Float16)stA; xB[1]=(_Float16)stS;
            xB[2]=(_Float16)1.0f;
        }
        // prefetch next step's features (hidden behind MFMA phase)
        const int t2 = (t < HH-1) ? t+1 : HH-1;
        f32x4 fN = *(const f32x4*)&policy[(size_t)row*(HH*4) + 4*t2];
        // noise for this step (L1-resident; latency overlapped by MFMA phase)
        float nT = noiseT[(size_t)row*HH + t];
        float nD = noiseD[(size_t)row*HH + t];

        // ---- fused layers 1+2: all in registers, no LDS ----
        f32x4 acc0 = b2v4[0], acc1 = b2v4[1], acc2 = b2v4[2], acc3 = b2v4[3];
        const f32x4 z4 = {0.f,0.f,0.f,0.f};
        #pragma unroll
        for (int kc = 0; kc < 8; ++kc) {
            f32x4 gE = __builtin_amdgcn_mfma_f32_16x16x16f16(w1A[2*kc  ], xB, z4, 0, 0, 0);
            f32x4 gO = __builtin_amdgcn_mfma_f32_16x16x16f16(w1A[2*kc+1], xB, z4, 0, 0, 0);
            f16x2 h0 = __builtin_bit_cast(f16x2, __builtin_amdgcn_cvt_pkrtz(gE[0], gE[1]));
            f16x2 h1 = __builtin_bit_cast(f16x2, __builtin_amdgcn_cvt_pkrtz(gE[2], gE[3]));
            f16x2 h2 = __builtin_bit_cast(f16x2, __builtin_amdgcn_cvt_pkrtz(gO[0], gO[1]));
            f16x2 h3 = __builtin_bit_cast(f16x2, __builtin_amdgcn_cvt_pkrtz(gO[2], gO[3]));
            f16x8 hf = {h0[0],h0[1],h1[0],h1[1],h2[0],h2[1],h3[0],h3[1]};
            f16x8 zero8 = {};
            hf = __builtin_elementwise_max(hf, zero8);   // relu (v_pk_max_f16)
            acc0 = __builtin_amdgcn_mfma_f32_16x16x32_f16(bfr[0][kc], hf, acc0, 0, 0, 0);
            acc1 = __builtin_amdgcn_mfma_f32_16x16x32_f16(bfr[1][kc], hf, acc1, 0, 0, 0);
            acc2 = __builtin_amdgcn_mfma_f32_16x16x32_f16(bfr[2][kc], hf, acc2, 0, 0, 0);
            acc3 = __builtin_amdgcn_mfma_f32_16x16x32_f16(bfr[3][kc], hf, acc3, 0, 0, 0);
        }

        // ---- layer 3: in-lane w3-dot, then cross-lq shfl reduce, wave partial ----
        f32x4 zz = {0.f,0.f,0.f,0.f};
        f32x4 vv = w3v4[0] * __builtin_elementwise_max(acc0, zz);
        vv += w3v4[1] * __builtin_elementwise_max(acc1, zz);
        vv += w3v4[2] * __builtin_elementwise_max(acc2, zz);
        vv += w3v4[3] * __builtin_elementwise_max(acc3, zz);
        float v = (vv[0] + vv[1]) + (vv[2] + vv[3]);
        v += __shfl_xor(v, 16);
        v += __shfl_xor(v, 32);      // sum over this wave's 64 neurons
        if (lane < 16) partialLDS[lane*4 + wave] = v;
        __syncthreads();             // bar A: partials visible

        // ---- recurrence (replicated across lq/wave) ----
        f32x4 q = *(const f32x4*)&partialLDS[l16*4];
        float e    = __builtin_exp2f(2.0f*(float)t - 190.0f);   // 0.25^(95-t)
        float ft   = 0.5f * (1.0f - e);
        float Gam  = 2.0f + ft;
        float invG = __builtin_amdgcn_rcpf(Gam);
        float bcoef = lam*2.0f + budH*((float)t + 2.0f);
        float psum = (q[0] + q[1]) + (q[2] + q[3]);
        float a_ml   = fmaxf(psum + b3s, 0.0f);
        float a_prior = fminf(fmaxf(stS + dem, 0.0f) * 1.25f, 10.0f);
        float sgn    = (a_ml < a_prior) ? 1.0f : -1.0f;
        float a_out  = fmaf(fmaxf(fabsf(a_ml - a_prior) - stB * invG, 0.0f), sgn, a_ml);
        float ns     = fminf(fmaxf(stS * (1.0f - nD) + dem - (0.8f + nT) * a_out, 0.0f), 15.0f);
        float c_cost = fmaf(fmaf(0.1f, ns, 1.0f), ns, 2.0f);
        float ad_new = fabsf(a_out - a_prior);
        float cum_dv = fmaf(2.0f, ad_new, 0.375f * stSS);
        float c_prior = fmaxf(2.0f, c_cost - cum_dv);
        float cum_c_new = stC + (1.0f + lam) * c_prior - c_cost;
        float T      = fmaf(0.25f, stSS, ad_new);
        float cum_dg = ft * T;
        float bgt_if = fmaxf(fmaxf(stB + per_step - ad_new * Gam, 0.0f),
                             cum_c_new - cum_dg + bcoef);
        float bgt_else = fmaxf(stB + per_step - stAD * Gam, 0.0f);
        if (t == HH - 1) { stB = bgt_else; }
        else             { stB = bgt_if; stC = cum_c_new; }
        stSS = T;
        stAD = ad_new;
        stA  = a_out;
        stS  = ns;
        if (tid < MROWS) outLDS[tid*OSTR + t] = a_out;
        f = fN;
        __syncthreads();             // bar B: all reads done before next write
    }

    // ---- coalesced output dump (outLDS writes covered by final bar B) ----
    float* oslice = out + (size_t)r0 * HH;
    #pragma unroll
    for (int i = 0; i < 3; ++i) {
        int idx = (i*256 + tid) * 2;               // 1536 dwords total
        int rr = idx / 96, c = idx - rr*96;        // pairs never straddle rows
        f32x2 v = { outLDS[rr*OSTR + c], outLDS[rr*OSTR + c + 1] };
        *(f32x2*)&oslice[idx] = v;
    }
}

extern "C" void kernel_launch(void* const* d_in, const int* in_sizes, int n_in,
                              void* d_out, int out_size, void* d_ws, size_t ws_size,
                              hipStream_t stream) {
    policy_scan_kernel<<<dim3(8192 / MROWS), dim3(256), 0, stream>>>(
        (const float*)d_in[0],  // policy_in_c
        (const float*)d_in[1],  // trans_noise
        (const float*)d_in[2],  // demand_noise
        (const float*)d_in[3],  // action_pre
        (const float*)d_in[4],  // state_pre
        (const float*)d_in[5],  // Lambda
        (const float*)d_in[6],  // Budget
        (const float*)d_in[7],  // W1
        (const float*)d_in[8],  // b1
        (const float*)d_in[9],  // W2
        (const float*)d_in[10], // b2
        (const float*)d_in[11], // W3
        (const float*)d_in[12], // b3
        (float*)d_out);
}

// Round 9
// 240.110 us; speedup vs baseline: 1.0309x; 1.0309x over previous
//
#include <hip/hip_runtime.h>
#include <stdint.h>
#include <stddef.h>

typedef float    f32x4 __attribute__((ext_vector_type(4)));
typedef float    f32x2 __attribute__((ext_vector_type(2)));
typedef _Float16 f16x4 __attribute__((ext_vector_type(4)));
typedef _Float16 f16x8 __attribute__((ext_vector_type(8)));
typedef _Float16 f16x2 __attribute__((ext_vector_type(2)));

#define HH 96
#define MROWS 16
#define OSTR 100   // outLDS row stride (dwords)

// Layer-1 neuron permutation: tile T, C-slot m -> actual neuron index, chosen so
// the 16x16x16 layer-1 MFMA C-output lands exactly in the 16x16x32 layer-2
// B-fragment layout (k = kc*32 + lq*8 + j) with zero cross-lane movement:
//   a(2kc+p, 4lq+r) = 32kc + 8lq + 4p + r.
__device__ __forceinline__ int permA(int T, int m) {
    return 32*(T>>1) + 8*(m>>2) + 4*(T&1) + (m&3);
}

__launch_bounds__(256, 2)
__global__ void policy_scan_kernel(
    const float* __restrict__ policy,     // (B,96,4)
    const float* __restrict__ noiseT,     // (B,96)
    const float* __restrict__ noiseD,     // (B,96)
    const float* __restrict__ action_pre, // (B,)
    const float* __restrict__ state_pre,  // (B,)
    const float* __restrict__ Lambda1,    // (1,)
    const float* __restrict__ Budget1,    // (1,)
    const float* __restrict__ W1,         // (256,6)
    const float* __restrict__ b1,         // (256,)
    const float* __restrict__ W2,         // (256,256)
    const float* __restrict__ b2,         // (256,)
    const float* __restrict__ W3,         // (256,)
    const float* __restrict__ b3,         // (1,)
    float* __restrict__ out)              // (B,96)
{
    __shared__ __attribute__((aligned(16))) float partialLDS[64];     // [l16*4+wave]
    __shared__ __attribute__((aligned(16))) float outLDS[MROWS*OSTR]; // 6400 B
    __shared__ __attribute__((aligned(16))) float b2LDS[256];         // 1 KB
    __shared__ __attribute__((aligned(16))) float w3LDS[256];         // 1 KB

    const int tid  = threadIdx.x;          // 0..255
    const int wave = tid >> 6;             // 0..3
    const int lane = tid & 63;
    const int l16  = lane & 15;
    const int lq   = lane >> 4;            // 0..3
    const int r0   = blockIdx.x * MROWS;
    const int row  = r0 + l16;             // this lane's batch row (replicated x16)

    // ---- zero/const init of ALL LDS we read (identical behavior every launch) ----
    if (tid < 64) partialLDS[tid] = 0.0f;
    #pragma unroll
    for (int i = 0; i < 7; ++i) {
        int j = i*256 + tid;
        if (j < MROWS*OSTR) outLDS[j] = 0.0f;
    }
    b2LDS[tid] = b2[tid];
    w3LDS[tid] = W3[tid];

    // ---- W2 -> fp16 A-frags (A[m=n2][k]): lane (l16,lq) holds
    // W2[n2 = wave*64+tt*16+l16][k = kc*32+lq*8+j]  (128 regs, MFMA-only -> AGPR) ----
    f16x8 bfr[4][8];
    #pragma unroll
    for (int tt = 0; tt < 4; ++tt) {
        const int n = wave*64 + tt*16 + l16;
        const float* wrow = W2 + (size_t)n * 256;
        #pragma unroll
        for (int kc = 0; kc < 8; ++kc) {
            const int k0 = kc*32 + lq*8;
            f32x4 u0 = *(const f32x4*)(wrow + k0);
            f32x4 u1 = *(const f32x4*)(wrow + k0 + 4);
            f16x8 v;
            v[0]=(_Float16)u0[0]; v[1]=(_Float16)u0[1]; v[2]=(_Float16)u0[2]; v[3]=(_Float16)u0[3];
            v[4]=(_Float16)u1[0]; v[5]=(_Float16)u1[1]; v[6]=(_Float16)u1[2]; v[7]=(_Float16)u1[3];
            bfr[tt][kc] = v;
        }
    }

    // ---- W1 -> permuted 16x16x16 A-frags (16 regs, MFMA-only); bias at k=6 ----
    f16x4 w1A[16];
    #pragma unroll
    for (int T = 0; T < 16; ++T) {
        const int a = permA(T, l16);
        f16x4 w = {};
        if (lq == 0) {
            w[0]=(_Float16)W1[a*6+0]; w[1]=(_Float16)W1[a*6+1];
            w[2]=(_Float16)W1[a*6+2]; w[3]=(_Float16)W1[a*6+3];
        } else if (lq == 1) {
            w[0]=(_Float16)W1[a*6+4]; w[1]=(_Float16)W1[a*6+5];
            w[2]=(_Float16)b1[a];     w[3]=(_Float16)0.0f;
        }
        w1A[T] = w;
    }

    const float lam  = Lambda1[0];
    const float budH = Budget1[0] * (1.0f/96.0f);
    const float b3s  = b3[0];
    const float per_step = lam * 2.0f + budH;
    const int   cbase = wave*64 + lq*4;    // phase-C LDS base (broadcast per 16 lanes)

    // ---- recurrence state for row l16 (replicated across lq & waves) ----
    float stA = action_pre[row];
    float stS = state_pre[row];
    float stB = per_step, stC = 0.0f, stSS = 0.0f, stAD = 0.0f;

    const float* prow = policy + (size_t)row * (HH*4);
    const float* nTrow = noiseT + (size_t)row * HH;
    const float* nDrow = noiseD + (size_t)row * HH;

    // first step's features (prefetched; later steps prefetch in-loop)
    f32x4 f = *(const f32x4*)prow;

    __syncthreads();   // LDS init complete

    #pragma unroll 1
    for (int t = 0; t < HH; ++t) {
        const float dem = f[0];
        // x B-frag for layer 1 (k = lq*4+j): lq0={feat}, lq1={stA,stS,1,0}
        f16x4 xB = {};
        if (lq == 0) {
            xB[0]=(_Float16)f[0]; xB[1]=(_Float16)f[1];
            xB[2]=(_Float16)f[2]; xB[3]=(_Float16)f[3];
        } else if (lq == 1) {
            xB[0]=(_Float16)stA; xB[1]=(_Float16)stS;
            xB[2]=(_Float16)1.0f;
        }
        // prefetch next step's features + this step's noise (hidden behind MFMAs)
        const int t2 = (t < HH-1) ? t+1 : HH-1;
        f32x4 fN = *(const f32x4*)(prow + 4*t2);
        float nT = nTrow[t];
        float nD = nDrow[t];

        // ---- fused layers 1+2: all in registers; acc starts from inline zero ----
        f32x4 acc0, acc1, acc2, acc3;
        const f32x4 z4 = {0.f,0.f,0.f,0.f};
        #pragma unroll
        for (int kc = 0; kc < 8; ++kc) {
            f32x4 gE = __builtin_amdgcn_mfma_f32_16x16x16f16(w1A[2*kc  ], xB, z4, 0, 0, 0);
            f32x4 gO = __builtin_amdgcn_mfma_f32_16x16x16f16(w1A[2*kc+1], xB, z4, 0, 0, 0);
            f16x2 h0 = __builtin_bit_cast(f16x2, __builtin_amdgcn_cvt_pkrtz(gE[0], gE[1]));
            f16x2 h1 = __builtin_bit_cast(f16x2, __builtin_amdgcn_cvt_pkrtz(gE[2], gE[3]));
            f16x2 h2 = __builtin_bit_cast(f16x2, __builtin_amdgcn_cvt_pkrtz(gO[0], gO[1]));
            f16x2 h3 = __builtin_bit_cast(f16x2, __builtin_amdgcn_cvt_pkrtz(gO[2], gO[3]));
            f16x8 hf = {h0[0],h0[1],h1[0],h1[1],h2[0],h2[1],h3[0],h3[1]};
            f16x8 zero8 = {};
            hf = __builtin_elementwise_max(hf, zero8);   // relu (v_pk_max_f16)
            if (kc == 0) {
                acc0 = __builtin_amdgcn_mfma_f32_16x16x32_f16(bfr[0][0], hf, z4, 0, 0, 0);
                acc1 = __builtin_amdgcn_mfma_f32_16x16x32_f16(bfr[1][0], hf, z4, 0, 0, 0);
                acc2 = __builtin_amdgcn_mfma_f32_16x16x32_f16(bfr[2][0], hf, z4, 0, 0, 0);
                acc3 = __builtin_amdgcn_mfma_f32_16x16x32_f16(bfr[3][0], hf, z4, 0, 0, 0);
            } else {
                acc0 = __builtin_amdgcn_mfma_f32_16x16x32_f16(bfr[0][kc], hf, acc0, 0, 0, 0);
                acc1 = __builtin_amdgcn_mfma_f32_16x16x32_f16(bfr[1][kc], hf, acc1, 0, 0, 0);
                acc2 = __builtin_amdgcn_mfma_f32_16x16x32_f16(bfr[2][kc], hf, acc2, 0, 0, 0);
                acc3 = __builtin_amdgcn_mfma_f32_16x16x32_f16(bfr[3][kc], hf, acc3, 0, 0, 0);
            }
        }

        // ---- layer 3: +b2, relu, dot w3 (b2/w3 via broadcast LDS reads) ----
        f32x4 zz = {0.f,0.f,0.f,0.f};
        f32x4 vv = zz;
        {
            f32x4 bb0 = *(const f32x4*)&b2LDS[cbase     ];
            f32x4 ww0 = *(const f32x4*)&w3LDS[cbase     ];
            f32x4 bb1 = *(const f32x4*)&b2LDS[cbase + 16];
            f32x4 ww1 = *(const f32x4*)&w3LDS[cbase + 16];
            vv += ww0 * __builtin_elementwise_max(acc0 + bb0, zz);
            vv += ww1 * __builtin_elementwise_max(acc1 + bb1, zz);
            f32x4 bb2 = *(const f32x4*)&b2LDS[cbase + 32];
            f32x4 ww2 = *(const f32x4*)&w3LDS[cbase + 32];
            f32x4 bb3 = *(const f32x4*)&b2LDS[cbase + 48];
            f32x4 ww3 = *(const f32x4*)&w3LDS[cbase + 48];
            vv += ww2 * __builtin_elementwise_max(acc2 + bb2, zz);
            vv += ww3 * __builtin_elementwise_max(acc3 + bb3, zz);
        }
        float v = (vv[0] + vv[1]) + (vv[2] + vv[3]);
        v += __shfl_xor(v, 16);
        v += __shfl_xor(v, 32);      // sum over this wave's 64 neurons
        if (lane < 16) partialLDS[lane*4 + wave] = v;
        __syncthreads();             // bar A: partials visible

        // ---- recurrence (replicated across lq/wave) ----
        f32x4 q = *(const f32x4*)&partialLDS[l16*4];
        float e    = __builtin_exp2f(2.0f*(float)t - 190.0f);   // 0.25^(95-t)
        float ft   = 0.5f * (1.0f - e);
        float Gam  = 2.0f + ft;
        float invG = __builtin_amdgcn_rcpf(Gam);
        float bcoef = lam*2.0f + budH*((float)t + 2.0f);
        float psum = (q[0] + q[1]) + (q[2] + q[3]);
        float a_ml   = fmaxf(psum + b3s, 0.0f);
        float a_prior = fminf(fmaxf(stS + dem, 0.0f) * 1.25f, 10.0f);
        float sgn    = (a_ml < a_prior) ? 1.0f : -1.0f;
        float a_out  = fmaf(fmaxf(fabsf(a_ml - a_prior) - stB * invG, 0.0f), sgn, a_ml);
        float ns     = fminf(fmaxf(stS * (1.0f - nD) + dem - (0.8f + nT) * a_out, 0.0f), 15.0f);
        float c_cost = fmaf(fmaf(0.1f, ns, 1.0f), ns, 2.0f);
        float ad_new = fabsf(a_out - a_prior);
        float cum_dv = fmaf(2.0f, ad_new, 0.375f * stSS);
        float c_prior = fmaxf(2.0f, c_cost - cum_dv);
        float cum_c_new = stC + (1.0f + lam) * c_prior - c_cost;
        float T      = fmaf(0.25f, stSS, ad_new);
        float cum_dg = ft * T;
        float bgt_if = fmaxf(fmaxf(stB + per_step - ad_new * Gam, 0.0f),
                             cum_c_new - cum_dg + bcoef);
        float bgt_else = fmaxf(stB + per_step - stAD * Gam, 0.0f);
        if (t == HH - 1) { stB = bgt_else; }
        else             { stB = bgt_if; stC = cum_c_new; }
        stSS = T;
        stAD = ad_new;
        stA  = a_out;
        stS  = ns;
        if (tid < MROWS) outLDS[tid*OSTR + t] = a_out;
        f = fN;
        __syncthreads();             // bar B: all reads done before next write
    }

    // ---- coalesced output dump (outLDS writes covered by final bar B) ----
    float* oslice = out + (size_t)r0 * HH;
    #pragma unroll
    for (int i = 0; i < 3; ++i) {
        int idx = (i*256 + tid) * 2;               // 1536 dwords total
        int rr = idx / 96, c = idx - rr*96;        // pairs never straddle rows
        f32x2 v = { outLDS[rr*OSTR + c], outLDS[rr*OSTR + c + 1] };
        *(f32x2*)&oslice[idx] = v;
    }
}

extern "C" void kernel_launch(void* const* d_in, const int* in_sizes, int n_in,
                              void* d_out, int out_size, void* d_ws, size_t ws_size,
                              hipStream_t stream) {
    policy_scan_kernel<<<dim3(8192 / MROWS), dim3(256), 0, stream>>>(
        (const float*)d_in[0],  // policy_in_c
        (const float*)d_in[1],  // trans_noise
        (const float*)d_in[2],  // demand_noise
        (const float*)d_in[3],  // action_pre
        (const float*)d_in[4],  // state_pre
        (const float*)d_in[5],  // Lambda
        (const float*)d_in[6],  // Budget
        (const float*)d_in[7],  // W1
        (const float*)d_in[8],  // b1
        (const float*)d_in[9],  // W2
        (const float*)d_in[10], // b2
        (const float*)d_in[11], // W3
        (const float*)d_in[12], // b3
        (float*)d_out);
}

// Round 10
// 238.355 us; speedup vs baseline: 1.0385x; 1.0074x over previous
//
#include <hip/hip_runtime.h>
#include <stdint.h>
#include <stddef.h>

typedef float    f32x4 __attribute__((ext_vector_type(4)));
typedef float    f32x2 __attribute__((ext_vector_type(2)));
typedef _Float16 f16x4 __attribute__((ext_vector_type(4)));
typedef _Float16 f16x8 __attribute__((ext_vector_type(8)));
typedef _Float16 f16x2 __attribute__((ext_vector_type(2)));

#define HH 96
#define MROWS 16
#define OSTR 100   // outLDS row stride (dwords)
#define NSTR 32    // noiseTD per-t stride in dwords (16 rows x float2)

// Layer-1 neuron permutation: tile T, C-slot m -> actual neuron index, chosen so
// the 16x16x16 layer-1 MFMA C-output lands exactly in the 16x16x32 layer-2
// B-fragment layout (k = kc*32 + lq*8 + j) with zero cross-lane movement:
//   a(2kc+p, 4lq+r) = 32kc + 8lq + 4p + r.
__device__ __forceinline__ int permA(int T, int m) {
    return 32*(T>>1) + 8*(m>>2) + 4*(T&1) + (m&3);
}

__launch_bounds__(256, 2)
__global__ void policy_scan_kernel(
    const float* __restrict__ policy,     // (B,96,4)
    const float* __restrict__ noiseT,     // (B,96)
    const float* __restrict__ noiseD,     // (B,96)
    const float* __restrict__ action_pre, // (B,)
    const float* __restrict__ state_pre,  // (B,)
    const float* __restrict__ Lambda1,    // (1,)
    const float* __restrict__ Budget1,    // (1,)
    const float* __restrict__ W1,         // (256,6)
    const float* __restrict__ b1,         // (256,)
    const float* __restrict__ W2,         // (256,256)
    const float* __restrict__ b2,         // (256,)
    const float* __restrict__ W3,         // (256,)
    const float* __restrict__ b3,         // (1,)
    float* __restrict__ out)              // (B,96)
{
    __shared__ __attribute__((aligned(16))) float featLDS[HH*MROWS*4];  // [t][row][4] 24576 B
    __shared__ __attribute__((aligned(16))) float noiseTD[HH*NSTR];     // [t][row][2] 12288 B
    __shared__ __attribute__((aligned(16))) float partialLDS[64];       // [l16*4+wave]
    __shared__ __attribute__((aligned(16))) float outLDS[MROWS*OSTR];   // 6400 B
    __shared__ __attribute__((aligned(16))) float b2LDS[256];           // 1 KB
    __shared__ __attribute__((aligned(16))) float w3LDS[256];           // 1 KB

    const int tid  = threadIdx.x;          // 0..255
    const int wave = tid >> 6;             // 0..3
    const int lane = tid & 63;
    const int l16  = lane & 15;
    const int lq   = lane >> 4;            // 0..3
    const int r0   = blockIdx.x * MROWS;
    const int row  = r0 + l16;             // this lane's batch row (replicated x16)

    // ---- stage ALL per-block inputs into LDS upfront (coalesced; keeps the
    // per-step loop free of global loads -> no vmcnt(0) drain at barriers) ----
    {
        const f32x4* src = (const f32x4*)(policy + (size_t)r0 * HH * 4);
        #pragma unroll
        for (int i = 0; i < 6; ++i) {
            int idx = i*256 + tid;                 // idx = row*96 + t
            int rr = idx / 96, t = idx - rr*96;
            *(f32x4*)&featLDS[(t*MROWS + rr)*4] = src[idx];
        }
        const float* s1 = noiseT + (size_t)r0 * HH;
        const float* s2 = noiseD + (size_t)r0 * HH;
        #pragma unroll
        for (int i = 0; i < 6; ++i) {
            int idx = i*256 + tid;
            int rr = idx / 96, t = idx - rr*96;
            noiseTD[t*NSTR + rr*2    ] = s1[idx];
            noiseTD[t*NSTR + rr*2 + 1] = s2[idx];
        }
    }
    // ---- zero/const init of remaining LDS we read ----
    if (tid < 64) partialLDS[tid] = 0.0f;
    #pragma unroll
    for (int i = 0; i < 7; ++i) {
        int j = i*256 + tid;
        if (j < MROWS*OSTR) outLDS[j] = 0.0f;
    }
    b2LDS[tid] = b2[tid];
    w3LDS[tid] = W3[tid];

    // ---- W2 -> fp16 A-frags (A[m=n2][k]): lane (l16,lq) holds
    // W2[n2 = wave*64+tt*16+l16][k = kc*32+lq*8+j]  (128 regs) ----
    f16x8 bfr[4][8];
    #pragma unroll
    for (int tt = 0; tt < 4; ++tt) {
        const int n = wave*64 + tt*16 + l16;
        const float* wrow = W2 + (size_t)n * 256;
        #pragma unroll
        for (int kc = 0; kc < 8; ++kc) {
            const int k0 = kc*32 + lq*8;
            f32x4 u0 = *(const f32x4*)(wrow + k0);
            f32x4 u1 = *(const f32x4*)(wrow + k0 + 4);
            f16x8 v;
            v[0]=(_Float16)u0[0]; v[1]=(_Float16)u0[1]; v[2]=(_Float16)u0[2]; v[3]=(_Float16)u0[3];
            v[4]=(_Float16)u1[0]; v[5]=(_Float16)u1[1]; v[6]=(_Float16)u1[2]; v[7]=(_Float16)u1[3];
            bfr[tt][kc] = v;
        }
    }

    // ---- W1 -> permuted 16x16x16 A-frags; bias folded at k=6 ----
    f16x4 w1A[16];
    #pragma unroll
    for (int T = 0; T < 16; ++T) {
        const int a = permA(T, l16);
        f16x4 w = {};
        if (lq == 0) {
            w[0]=(_Float16)W1[a*6+0]; w[1]=(_Float16)W1[a*6+1];
            w[2]=(_Float16)W1[a*6+2]; w[3]=(_Float16)W1[a*6+3];
        } else if (lq == 1) {
            w[0]=(_Float16)W1[a*6+4]; w[1]=(_Float16)W1[a*6+5];
            w[2]=(_Float16)b1[a];     w[3]=(_Float16)0.0f;
        }
        w1A[T] = w;
    }

    const float lam  = Lambda1[0];
    const float budH = Budget1[0] * (1.0f/96.0f);
    const float b3s  = b3[0];
    const float per_step = lam * 2.0f + budH;
    const int   cbase = wave*64 + lq*4;    // phase-C LDS base (broadcast per 16 lanes)

    // ---- recurrence state for row l16 (replicated across lq & waves) ----
    float stA = action_pre[row];
    float stS = state_pre[row];
    float stB = per_step, stC = 0.0f, stSS = 0.0f, stAD = 0.0f;

    __syncthreads();   // staging + LDS init complete

    #pragma unroll 1
    for (int t = 0; t < HH; ++t) {
        // ---- per-step inputs from LDS (short-latency, conflict-light) ----
        f32x4 f  = *(const f32x4*)&featLDS[(t*MROWS + l16)*4];
        f32x2 nz = *(const f32x2*)&noiseTD[t*NSTR + l16*2];
        const float dem = f[0];
        // x B-frag for layer 1 (k = lq*4+j): lq0={feat}, lq1={stA,stS,1,0}
        f16x4 xB = {};
        if (lq == 0) {
            xB[0]=(_Float16)f[0]; xB[1]=(_Float16)f[1];
            xB[2]=(_Float16)f[2]; xB[3]=(_Float16)f[3];
        } else if (lq == 1) {
            xB[0]=(_Float16)stA; xB[1]=(_Float16)stS;
            xB[2]=(_Float16)1.0f;
        }

        // ---- fused layers 1+2: all in registers; acc starts from inline zero ----
        f32x4 acc0, acc1, acc2, acc3;
        const f32x4 z4 = {0.f,0.f,0.f,0.f};
        #pragma unroll
        for (int kc = 0; kc < 8; ++kc) {
            f32x4 gE = __builtin_amdgcn_mfma_f32_16x16x16f16(w1A[2*kc  ], xB, z4, 0, 0, 0);
            f32x4 gO = __builtin_amdgcn_mfma_f32_16x16x16f16(w1A[2*kc+1], xB, z4, 0, 0, 0);
            f16x2 h0 = __builtin_bit_cast(f16x2, __builtin_amdgcn_cvt_pkrtz(gE[0], gE[1]));
            f16x2 h1 = __builtin_bit_cast(f16x2, __builtin_amdgcn_cvt_pkrtz(gE[2], gE[3]));
            f16x2 h2 = __builtin_bit_cast(f16x2, __builtin_amdgcn_cvt_pkrtz(gO[0], gO[1]));
            f16x2 h3 = __builtin_bit_cast(f16x2, __builtin_amdgcn_cvt_pkrtz(gO[2], gO[3]));
            f16x8 hf = {h0[0],h0[1],h1[0],h1[1],h2[0],h2[1],h3[0],h3[1]};
            f16x8 zero8 = {};
            hf = __builtin_elementwise_max(hf, zero8);   // relu (v_pk_max_f16)
            if (kc == 0) {
                acc0 = __builtin_amdgcn_mfma_f32_16x16x32_f16(bfr[0][0], hf, z4, 0, 0, 0);
                acc1 = __builtin_amdgcn_mfma_f32_16x16x32_f16(bfr[1][0], hf, z4, 0, 0, 0);
                acc2 = __builtin_amdgcn_mfma_f32_16x16x32_f16(bfr[2][0], hf, z4, 0, 0, 0);
                acc3 = __builtin_amdgcn_mfma_f32_16x16x32_f16(bfr[3][0], hf, z4, 0, 0, 0);
            } else {
                acc0 = __builtin_amdgcn_mfma_f32_16x16x32_f16(bfr[0][kc], hf, acc0, 0, 0, 0);
                acc1 = __builtin_amdgcn_mfma_f32_16x16x32_f16(bfr[1][kc], hf, acc1, 0, 0, 0);
                acc2 = __builtin_amdgcn_mfma_f32_16x16x32_f16(bfr[2][kc], hf, acc2, 0, 0, 0);
                acc3 = __builtin_amdgcn_mfma_f32_16x16x32_f16(bfr[3][kc], hf, acc3, 0, 0, 0);
            }
        }

        // ---- layer 3: +b2, relu, dot w3 (b2/w3 via broadcast LDS reads) ----
        f32x4 zz = {0.f,0.f,0.f,0.f};
        f32x4 vv = zz;
        {
            f32x4 bb0 = *(const f32x4*)&b2LDS[cbase     ];
            f32x4 ww0 = *(const f32x4*)&w3LDS[cbase     ];
            f32x4 bb1 = *(const f32x4*)&b2LDS[cbase + 16];
            f32x4 ww1 = *(const f32x4*)&w3LDS[cbase + 16];
            vv += ww0 * __builtin_elementwise_max(acc0 + bb0, zz);
            vv += ww1 * __builtin_elementwise_max(acc1 + bb1, zz);
            f32x4 bb2 = *(const f32x4*)&b2LDS[cbase + 32];
            f32x4 ww2 = *(const f32x4*)&w3LDS[cbase + 32];
            f32x4 bb3 = *(const f32x4*)&b2LDS[cbase + 48];
            f32x4 ww3 = *(const f32x4*)&w3LDS[cbase + 48];
            vv += ww2 * __builtin_elementwise_max(acc2 + bb2, zz);
            vv += ww3 * __builtin_elementwise_max(acc3 + bb3, zz);
        }
        float v = (vv[0] + vv[1]) + (vv[2] + vv[3]);
        v += __shfl_xor(v, 16);
        v += __shfl_xor(v, 32);      // sum over this wave's 64 neurons
        if (lane < 16) partialLDS[lane*4 + wave] = v;
        __syncthreads();             // bar A: partials visible

        // ---- recurrence (replicated across lq/wave) ----
        f32x4 q = *(const f32x4*)&partialLDS[l16*4];
        float e    = __builtin_exp2f(2.0f*(float)t - 190.0f);   // 0.25^(95-t)
        float ft   = 0.5f * (1.0f - e);
        float Gam  = 2.0f + ft;
        float invG = __builtin_amdgcn_rcpf(Gam);
        float bcoef = lam*2.0f + budH*((float)t + 2.0f);
        float psum = (q[0] + q[1]) + (q[2] + q[3]);
        float a_ml   = fmaxf(psum + b3s, 0.0f);
        float a_prior = fminf(fmaxf(stS + dem, 0.0f) * 1.25f, 10.0f);
        float sgn    = (a_ml < a_prior) ? 1.0f : -1.0f;
        float a_out  = fmaf(fmaxf(fabsf(a_ml - a_prior) - stB * invG, 0.0f), sgn, a_ml);
        float ns     = fminf(fmaxf(stS * (1.0f - nz[1]) + dem - (0.8f + nz[0]) * a_out, 0.0f), 15.0f);
        float c_cost = fmaf(fmaf(0.1f, ns, 1.0f), ns, 2.0f);
        float ad_new = fabsf(a_out - a_prior);
        float cum_dv = fmaf(2.0f, ad_new, 0.375f * stSS);
        float c_prior = fmaxf(2.0f, c_cost - cum_dv);
        float cum_c_new = stC + (1.0f + lam) * c_prior - c_cost;
        float T      = fmaf(0.25f, stSS, ad_new);
        float cum_dg = ft * T;
        float bgt_if = fmaxf(fmaxf(stB + per_step - ad_new * Gam, 0.0f),
                             cum_c_new - cum_dg + bcoef);
        float bgt_else = fmaxf(stB + per_step - stAD * Gam, 0.0f);
        if (t == HH - 1) { stB = bgt_else; }
        else             { stB = bgt_if; stC = cum_c_new; }
        stSS = T;
        stAD = ad_new;
        stA  = a_out;
        stS  = ns;
        if (tid < MROWS) outLDS[tid*OSTR + t] = a_out;
        __syncthreads();             // bar B: all reads done before next write
    }

    // ---- coalesced output dump (outLDS writes covered by final bar B) ----
    float* oslice = out + (size_t)r0 * HH;
    #pragma unroll
    for (int i = 0; i < 3; ++i) {
        int idx = (i*256 + tid) * 2;               // 1536 dwords total
        int rr = idx / 96, c = idx - rr*96;        // pairs never straddle rows
        f32x2 v = { outLDS[rr*OSTR + c], outLDS[rr*OSTR + c + 1] };
        *(f32x2*)&oslice[idx] = v;
    }
}

extern "C" void kernel_launch(void* const* d_in, const int* in_sizes, int n_in,
                              void* d_out, int out_size, void* d_ws, size_t ws_size,
                              hipStream_t stream) {
    policy_scan_kernel<<<dim3(8192 / MROWS), dim3(256), 0, stream>>>(
        (const float*)d_in[0],  // policy_in_c
        (const float*)d_in[1],  // trans_noise
        (const float*)d_in[2],  // demand_noise
        (const float*)d_in[3],  // action_pre
        (const float*)d_in[4],  // state_pre
        (const float*)d_in[5],  // Lambda
        (const float*)d_in[6],  // Budget
        (const float*)d_in[7],  // W1
        (const float*)d_in[8],  // b1
        (const float*)d_in[9],  // W2
        (const float*)d_in[10], // b2
        (const float*)d_in[11], // W3
        (const float*)d_in[12], // b3
        (float*)d_out);
}